// Round 1
// baseline (1042.718 us; speedup 1.0000x reference)
//
#include <hip/hip_runtime.h>
#include <math.h>

#define N_NODES 16384
#define N_EDGES 65536
#define N_GRAPH 128
#define TN 8

// ---------------------------------------------------------------- CSR build
__global__ __launch_bounds__(256) void k_hist(const int* __restrict__ esrc,
                                              const int* __restrict__ edst,
                                              int* __restrict__ deg,
                                              int* __restrict__ cntd) {
    int i = blockIdx.x * 256 + threadIdx.x;
    if (i < N_EDGES) {
        atomicAdd(&deg[esrc[i]], 1);
        atomicAdd(&cntd[edst[i]], 1);
    }
}

__global__ __launch_bounds__(256) void k_scan(const int* __restrict__ deg,
                                              int* __restrict__ soff,
                                              int* __restrict__ cursor) {
    __shared__ int part[256];
    int tid = threadIdx.x;
    int base = tid * 64;
    int s = 0;
    for (int i = 0; i < 64; ++i) s += deg[base + i];
    part[tid] = s;
    __syncthreads();
    for (int d = 1; d < 256; d <<= 1) {
        int add = (tid >= d) ? part[tid - d] : 0;
        __syncthreads();
        part[tid] += add;
        __syncthreads();
    }
    int run = (tid == 0) ? 0 : part[tid - 1];
    for (int i = 0; i < 64; ++i) {
        soff[base + i] = run;
        cursor[base + i] = run;
        run += deg[base + i];
    }
    if (tid == 255) soff[N_NODES] = run;
}

__global__ __launch_bounds__(256) void k_fill(const int* __restrict__ esrc,
                                              int* __restrict__ cursor,
                                              int* __restrict__ ebs) {
    int i = blockIdx.x * 256 + threadIdx.x;
    if (i < N_EDGES) {
        int p = atomicAdd(&cursor[esrc[i]], 1);
        ebs[p] = i;
    }
}

// ------------------------------------------------- [rows,64]@[64,64] GEMMs
// has_agg==0: xout = relu(xin@w + b)                       (lin0)
// has_agg==1: xout = relu(agg/max(cnt,1) + xin@w + b)      (NNConv root+agg)
__global__ __launch_bounds__(256) void k_rowgemm(const float* __restrict__ xin,
                                                 const float* __restrict__ w,
                                                 const float* __restrict__ b,
                                                 const float* __restrict__ aggv,
                                                 const int* __restrict__ cntd,
                                                 float* __restrict__ xout,
                                                 int has_agg) {
    __shared__ float As[64][64];
    __shared__ float Ws[64][64];
    __shared__ float bs[64];
    int tid = threadIdx.x;
    int n0 = blockIdx.x * 64;
    for (int i = tid; i < 4096; i += 256) {
        As[i >> 6][i & 63] = xin[n0 * 64 + i];
        Ws[i >> 6][i & 63] = w[i];
    }
    if (tid < 64) bs[tid] = b[tid];
    __syncthreads();
    int o = tid & 63, rr = tid >> 6;
    float acc[16];
#pragma unroll
    for (int i = 0; i < 16; ++i) acc[i] = bs[o];
    for (int d = 0; d < 64; ++d) {
        float wv = Ws[d][o];
#pragma unroll
        for (int i = 0; i < 16; ++i) acc[i] += As[rr * 16 + i][d] * wv;
    }
    for (int i = 0; i < 16; ++i) {
        int n = n0 + rr * 16 + i;
        float v = acc[i];
        if (has_agg) {
            float c = fmaxf((float)cntd[n], 1.f);
            v += aggv[n * 64 + o] / c;
        }
        xout[n * 64 + o] = fmaxf(v, 0.f);
    }
}

// ------------------------------------------------------------ fused NNConv
// Phase 1: P[t][k][o] = sum_d x[n0+t][d] * w2[k][d*64+o]   (in LDS only)
//          Bn[t][o]   = sum_d x[n0+t][d] * b2[d*64+o]
// Phase 2: per outgoing edge e of tile nodes:
//          h[e] = relu(ea[e]@w1+b1);  msg = h@P[t] + Bn[t]; atomicAdd agg[dst]
__global__ __launch_bounds__(256) void k_fused(
    const float* __restrict__ x, const float* __restrict__ ea,
    const int* __restrict__ esrc, const int* __restrict__ edst,
    const float* __restrict__ w1, const float* __restrict__ b1,
    const float* __restrict__ w2, const float* __restrict__ b2,
    const int* __restrict__ soff, const int* __restrict__ ebs,
    float* __restrict__ agg) {
    __shared__ __align__(16) float P[TN][64][64];   // 128 KB
    __shared__ __align__(16) float xs[TN][64];
    __shared__ __align__(16) float Bn[TN][64];
    __shared__ __align__(16) float w1s[16][64];
    __shared__ __align__(16) float b1s[64];
    __shared__ __align__(16) float hs[4][4][68];    // padded: bank-conflict-free

    const int tid = threadIdx.x;
    const int n0 = blockIdx.x * TN;
    const int o = tid & 63;
    const int wv = tid >> 6;

    for (int i = tid; i < TN * 64; i += 256) xs[i >> 6][i & 63] = x[n0 * 64 + i];
    for (int i = tid; i < 16 * 64; i += 256) w1s[i >> 6][i & 63] = w1[i];
    if (tid < 64) b1s[tid] = b1[tid];
    __syncthreads();

    // ---- phase 1: node-tile GEMM into LDS
    for (int p = 0; p < 4; ++p) {
        float acc[TN][4];
#pragma unroll
        for (int t = 0; t < TN; ++t)
#pragma unroll
            for (int j = 0; j < 4; ++j) acc[t][j] = 0.f;
#pragma unroll 4
        for (int d4 = 0; d4 < 16; ++d4) {
            float4 xr[TN];
#pragma unroll
            for (int t = 0; t < TN; ++t) xr[t] = *(const float4*)&xs[t][d4 * 4];
#pragma unroll
            for (int j = 0; j < 4; ++j) {
                const int k = p * 16 + j * 4 + wv;
                const float* wp = w2 + k * 4096 + d4 * 256 + o;
                const float wa = wp[0], wb = wp[64], wc = wp[128], wd = wp[192];
#pragma unroll
                for (int t = 0; t < TN; ++t)
                    acc[t][j] += wa * xr[t].x + wb * xr[t].y + wc * xr[t].z + wd * xr[t].w;
            }
        }
#pragma unroll
        for (int j = 0; j < 4; ++j) {
            const int k = p * 16 + j * 4 + wv;
#pragma unroll
            for (int t = 0; t < TN; ++t) P[t][k][o] = acc[t][j];
        }
    }
    if (wv == 0) {  // bias term (one wave; ~1/17 of phase-1 work)
        float acc[TN];
#pragma unroll
        for (int t = 0; t < TN; ++t) acc[t] = 0.f;
        for (int d = 0; d < 64; ++d) {
            const float bv = b2[d * 64 + o];
#pragma unroll
            for (int t = 0; t < TN; ++t) acc[t] += bv * xs[t][d];
        }
#pragma unroll
        for (int t = 0; t < TN; ++t) Bn[t][o] = acc[t];
    }
    __syncthreads();

    // ---- phase 2: edges of this tile; 4 edges per wave (16 lanes/edge)
    const int e_begin = soff[n0];
    const int cnt = soff[n0 + TN] - e_begin;
    const int e_sub = (tid >> 4) & 3;
    const int o4 = tid & 15;
    for (int eb = wv * 4; eb < cnt; eb += 16) {
        const int ei = eb + e_sub;
        if (ei < cnt) {
            const int e = ebs[e_begin + ei];
            const int t = esrc[e] - n0;
            const int dn = edst[e];
            const float* eap = ea + e * 16;
            // edge MLP: this lane computes h[o4*4 .. o4*4+3]
            float4 hb = *(const float4*)&b1s[o4 * 4];
            float h0 = hb.x, h1 = hb.y, h2 = hb.z, h3 = hb.w;
#pragma unroll
            for (int k = 0; k < 16; ++k) {
                const float av = eap[k];
                const float4 wv4 = *(const float4*)&w1s[k][o4 * 4];
                h0 += av * wv4.x; h1 += av * wv4.y; h2 += av * wv4.z; h3 += av * wv4.w;
            }
            h0 = fmaxf(h0, 0.f); h1 = fmaxf(h1, 0.f);
            h2 = fmaxf(h2, 0.f); h3 = fmaxf(h3, 0.f);
            *(float4*)&hs[wv][e_sub][o4 * 4] = make_float4(h0, h1, h2, h3);
            // contraction msg = h @ P[t] + Bn[t]  (same-wave LDS RAW: safe)
            float4 m = *(const float4*)&Bn[t][o4 * 4];
            for (int k = 0; k < 64; ++k) {
                const float hk = hs[wv][e_sub][k];
                const float4 pv = *(const float4*)&P[t][k][o4 * 4];
                m.x += hk * pv.x; m.y += hk * pv.y;
                m.z += hk * pv.z; m.w += hk * pv.w;
            }
            float* ap = agg + dn * 64 + o4 * 4;
            atomicAdd(ap + 0, m.x);
            atomicAdd(ap + 1, m.y);
            atomicAdd(ap + 2, m.z);
            atomicAdd(ap + 3, m.w);
        }
    }
}

// ----------------------------------------------------------------- GraphNorm
__global__ __launch_bounds__(256) void k_gnstats(const float* __restrict__ xc,
                                                 const float* __restrict__ gnscale,
                                                 float* __restrict__ mean,
                                                 float* __restrict__ rstd) {
    int g = blockIdx.x, tid = threadIdx.x;
    int c = tid & 63, rr = tid >> 6;
    float s = 0.f, s2 = 0.f;
    for (int r = rr; r < 128; r += 4) {
        float v = xc[(g * 128 + r) * 64 + c];
        s += v; s2 += v * v;
    }
    __shared__ float S[4][64], S2[4][64];
    S[rr][c] = s; S2[rr][c] = s2;
    __syncthreads();
    if (tid < 64) {
        float sum = S[0][tid] + S[1][tid] + S[2][tid] + S[3][tid];
        float sum2 = S2[0][tid] + S2[1][tid] + S2[2][tid] + S2[3][tid];
        float m = sum * (1.f / 128.f);
        float ex2 = sum2 * (1.f / 128.f);
        float sc = gnscale[tid];
        float var = ex2 - 2.f * sc * m * m + sc * sc * m * m;
        mean[g * 64 + tid] = m;
        rstd[g * 64 + tid] = rsqrtf(var + 1e-5f);
    }
}

__global__ __launch_bounds__(256) void k_gnapply(const float* __restrict__ xc,
                                                 const float* __restrict__ mean,
                                                 const float* __restrict__ rstd,
                                                 const float* __restrict__ gnscale,
                                                 const float* __restrict__ gw,
                                                 const float* __restrict__ gb,
                                                 float* __restrict__ x) {
    int idx = blockIdx.x * 256 + threadIdx.x;
    int c = idx & 63;
    int n = idx >> 6;
    int g = n >> 7;
    float sub = xc[idx] - gnscale[c] * mean[g * 64 + c];
    x[idx] = gw[c] * sub * rstd[g * 64 + c] + gb[c] + x[idx];
}

// ------------------------------------------------------------------ Set2Set
__global__ __launch_bounds__(256) void k_lstm(const float* __restrict__ q_star,
                                              float* __restrict__ hh,
                                              float* __restrict__ cc,
                                              const float* __restrict__ wih,
                                              const float* __restrict__ whh,
                                              const float* __restrict__ bih,
                                              const float* __restrict__ bhh) {
    int g = blockIdx.x, tid = threadIdx.x;
    __shared__ float qs[128];
    __shared__ float hsv[64];
    __shared__ float gl[256];
    if (tid < 128) qs[tid] = q_star[g * 128 + tid];
    else if (tid < 192) hsv[tid - 128] = hh[g * 64 + tid - 128];
    __syncthreads();
    float acc = bih[tid] + bhh[tid];
    const float* wr = wih + tid * 128;
    for (int i = 0; i < 128; ++i) acc += qs[i] * wr[i];
    const float* w2r = whh + tid * 64;
    for (int i = 0; i < 64; ++i) acc += hsv[i] * w2r[i];
    gl[tid] = acc;
    __syncthreads();
    if (tid < 64) {
        float ig = 1.f / (1.f + expf(-gl[tid]));
        float fg = 1.f / (1.f + expf(-gl[64 + tid]));
        float gg = tanhf(gl[128 + tid]);
        float og = 1.f / (1.f + expf(-gl[192 + tid]));
        float c = fg * cc[g * 64 + tid] + ig * gg;
        float h = og * tanhf(c);
        cc[g * 64 + tid] = c;
        hh[g * 64 + tid] = h;
    }
}

__global__ __launch_bounds__(256) void k_attn(const float* __restrict__ x,
                                              const float* __restrict__ hh,
                                              float* __restrict__ q_star) {
    int g = blockIdx.x, tid = threadIdx.x;
    __shared__ float qv[64];
    __shared__ float ev[128];
    __shared__ float S[4][64];
    __shared__ float red[2];
    if (tid < 64) qv[tid] = hh[g * 64 + tid];
    __syncthreads();
    if (tid < 128) {
        const float* xp = x + (g * 128 + tid) * 64;
        float s = 0.f;
        for (int c = 0; c < 64; ++c) s += xp[c] * qv[c];
        ev[tid] = s;
    }
    __syncthreads();
    if (tid < 64) {
        float m = fmaxf(ev[tid], ev[tid + 64]);
        for (int off = 32; off > 0; off >>= 1) m = fmaxf(m, __shfl_down(m, off));
        if (tid == 0) red[0] = m;
    }
    __syncthreads();
    float emax = red[0];
    if (tid < 128) ev[tid] = expf(ev[tid] - emax);
    __syncthreads();
    if (tid < 64) {
        float s = ev[tid] + ev[tid + 64];
        for (int off = 32; off > 0; off >>= 1) s += __shfl_down(s, off);
        if (tid == 0) red[1] = s;
    }
    __syncthreads();
    float denom = red[1];
    int c = tid & 63, rr = tid >> 6;
    float p = 0.f;
    for (int n = rr; n < 128; n += 4) p += ev[n] * x[(g * 128 + n) * 64 + c];
    S[rr][c] = p;
    __syncthreads();
    if (tid < 64) {
        float r = (S[0][tid] + S[1][tid] + S[2][tid] + S[3][tid]) / denom;
        q_star[g * 128 + tid] = qv[tid];
        q_star[g * 128 + 64 + tid] = r;
    }
}

// --------------------------------------------------------------------- head
__global__ __launch_bounds__(64) void k_head(const float* __restrict__ q_star,
                                             const float* __restrict__ w1,
                                             const float* __restrict__ b1,
                                             const float* __restrict__ w2,
                                             const float* __restrict__ b2,
                                             float* __restrict__ out) {
    int g = blockIdx.x, tid = threadIdx.x;
    __shared__ float qs[128];
    qs[tid] = q_star[g * 128 + tid];
    qs[64 + tid] = q_star[g * 128 + 64 + tid];
    __syncthreads();
    float acc = b1[tid];
    for (int i = 0; i < 128; ++i) acc += qs[i] * w1[i * 64 + tid];
    acc = fmaxf(acc, 0.f);
    float v = acc * w2[tid];
    for (int off = 32; off > 0; off >>= 1) v += __shfl_down(v, off);
    if (tid == 0) out[g] = v + b2[0];
}

// -------------------------------------------------------------------- launch
extern "C" void kernel_launch(void* const* d_in, const int* in_sizes, int n_in,
                              void* d_out, int out_size, void* d_ws, size_t ws_size,
                              hipStream_t stream) {
    (void)in_sizes; (void)n_in; (void)out_size; (void)ws_size;
    const float* x_in  = (const float*)d_in[0];
    const int*   eidx  = (const int*)d_in[1];
    const float* eattr = (const float*)d_in[2];
    const float* lin0w = (const float*)d_in[4];
    const float* lin0b = (const float*)d_in[5];
    const float* mw1   = (const float*)d_in[6];
    const float* mb1   = (const float*)d_in[7];
    const float* mw2   = (const float*)d_in[8];
    const float* mb2   = (const float*)d_in[9];
    const float* rootw = (const float*)d_in[10];
    const float* convb = (const float*)d_in[11];
    const float* gnw   = (const float*)d_in[12];
    const float* gnb   = (const float*)d_in[13];
    const float* gnsc  = (const float*)d_in[14];
    const float* wih   = (const float*)d_in[15];
    const float* whh   = (const float*)d_in[16];
    const float* bih   = (const float*)d_in[17];
    const float* bhh   = (const float*)d_in[18];
    const float* hw1   = (const float*)d_in[19];
    const float* hb1   = (const float*)d_in[20];
    const float* hw2   = (const float*)d_in[21];
    const float* hb2   = (const float*)d_in[22];
    float* out = (float*)d_out;

    const int* esrc = eidx;
    const int* edst = eidx + N_EDGES;

    float* xb    = (float*)d_ws;
    float* xcb   = xb + N_NODES * 64;
    float* agg   = xcb + N_NODES * 64;
    float* mean  = agg + N_NODES * 64;
    float* rstd  = mean + N_GRAPH * 64;
    float* qstar = rstd + N_GRAPH * 64;
    float* hhb   = qstar + N_GRAPH * 128;
    float* ccb   = hhb + N_GRAPH * 64;
    int* deg     = (int*)(ccb + N_GRAPH * 64);
    int* soff    = deg + N_NODES;
    int* cursor  = soff + (N_NODES + 1);
    int* cntd    = cursor + N_NODES;
    int* ebs     = cntd + N_NODES;

    hipMemsetAsync(deg, 0, sizeof(int) * (4 * N_NODES + 1 + N_EDGES), stream);
    hipMemsetAsync(qstar, 0, sizeof(float) * N_GRAPH * (128 + 64 + 64), stream);

    k_hist<<<N_EDGES / 256, 256, 0, stream>>>(esrc, edst, deg, cntd);
    k_scan<<<1, 256, 0, stream>>>(deg, soff, cursor);
    k_fill<<<N_EDGES / 256, 256, 0, stream>>>(esrc, cursor, ebs);

    k_rowgemm<<<N_NODES / 64, 256, 0, stream>>>(x_in, lin0w, lin0b, nullptr, nullptr, xb, 0);

    for (int l = 0; l < 3; ++l) {
        hipMemsetAsync(agg, 0, sizeof(float) * N_NODES * 64, stream);
        k_fused<<<N_NODES / TN, 256, 0, stream>>>(
            xb, eattr, esrc, edst,
            mw1 + l * 16 * 64, mb1 + l * 64,
            mw2 + l * 64 * 4096, mb2 + l * 4096,
            soff, ebs, agg);
        k_rowgemm<<<N_NODES / 64, 256, 0, stream>>>(xb, rootw + l * 4096, convb + l * 64,
                                                    agg, cntd, xcb, 1);
        k_gnstats<<<N_GRAPH, 256, 0, stream>>>(xcb, gnsc + l * 64, mean, rstd);
        k_gnapply<<<N_NODES * 64 / 256, 256, 0, stream>>>(xcb, mean, rstd, gnsc + l * 64,
                                                          gnw + l * 64, gnb + l * 64, xb);
    }

    for (int s = 0; s < 3; ++s) {
        k_lstm<<<N_GRAPH, 256, 0, stream>>>(qstar, hhb, ccb, wih, whh, bih, bhh);
        k_attn<<<N_GRAPH, 256, 0, stream>>>(xb, hhb, qstar);
    }
    k_head<<<N_GRAPH, 64, 0, stream>>>(qstar, hw1, hb1, hw2, hb2, out);
}

// Round 2
// 673.774 us; speedup vs baseline: 1.5476x; 1.5476x over previous
//
#include <hip/hip_runtime.h>
#include <hip/hip_bf16.h>
#include <math.h>

#define N_NODES 16384
#define N_EDGES 65536
#define N_GRAPH 128
#define TNF 32      // nodes per k_fused block
#define KC 4        // k-chunk size
#define NCH 16      // 64 / KC
#define CAP 192     // staged-edge capacity per 32-node tile (mean 128, +5.7 sigma)
#define MREG 12     // register message slots per 16-lane group (CAP/16)

typedef short s8v __attribute__((ext_vector_type(8)));
typedef float f4v __attribute__((ext_vector_type(4)));

__device__ inline void splitw(float v, unsigned short* hi, unsigned short* lo) {
    __hip_bfloat16 h = __float2bfloat16(v);
    float hf = __bfloat162float(h);
    __hip_bfloat16 l = __float2bfloat16(v - hf);
    *hi = *reinterpret_cast<unsigned short*>(&h);
    *lo = *reinterpret_cast<unsigned short*>(&l);
}

// ---------------------------------------------------------------- CSR build
__global__ __launch_bounds__(256) void k_hist(const int* __restrict__ esrc,
                                              const int* __restrict__ edst,
                                              int* __restrict__ deg,
                                              int* __restrict__ cntd) {
    int i = blockIdx.x * 256 + threadIdx.x;
    if (i < N_EDGES) {
        atomicAdd(&deg[esrc[i]], 1);
        atomicAdd(&cntd[edst[i]], 1);
    }
}

__global__ __launch_bounds__(256) void k_scan(const int* __restrict__ deg,
                                              int* __restrict__ soff,
                                              int* __restrict__ cursor) {
    __shared__ int part[256];
    int tid = threadIdx.x;
    int base = tid * 64;
    int s = 0;
    for (int i = 0; i < 64; ++i) s += deg[base + i];
    part[tid] = s;
    __syncthreads();
    for (int d = 1; d < 256; d <<= 1) {
        int add = (tid >= d) ? part[tid - d] : 0;
        __syncthreads();
        part[tid] += add;
        __syncthreads();
    }
    int run = (tid == 0) ? 0 : part[tid - 1];
    for (int i = 0; i < 64; ++i) {
        soff[base + i] = run;
        cursor[base + i] = run;
        run += deg[base + i];
    }
    if (tid == 255) soff[N_NODES] = run;
}

__global__ __launch_bounds__(256) void k_fill(const int* __restrict__ esrc,
                                              int* __restrict__ cursor,
                                              int* __restrict__ ebs) {
    int i = blockIdx.x * 256 + threadIdx.x;
    if (i < N_EDGES) {
        int p = atomicAdd(&cursor[esrc[i]], 1);
        ebs[p] = i;
    }
}

// ---------------------------------------------------- w2 fragment pre-pack
// W2F[l][k][s][o16][lane][j] (bf16 hi / lo):
//   = w2[l][k][(32*s + (lane>>4)*8 + j)*64 + o16*16 + (lane&15)]
// i.e. the exact B-fragment layout for mfma_f32_16x16x32_bf16:
//   B[k_dim = quad*8+j][col = lane&15].
__global__ __launch_bounds__(256) void k_w2prep(const float* __restrict__ w2,
                                                unsigned short* __restrict__ w2h,
                                                unsigned short* __restrict__ w2l) {
    int idx = blockIdx.x * 256 + threadIdx.x;   // 98304 total
    if (idx >= 3 * 64 * 2 * 4 * 64) return;
    int lane = idx & 63;
    int r = idx >> 6;
    int o16 = r & 3; r >>= 2;
    int s = r & 1; r >>= 1;
    int k = r & 63;
    int l = r >> 6;
    const float* src = w2 + l * 262144 + k * 4096;
    int o = o16 * 16 + (lane & 15);
    int d0 = s * 32 + (lane >> 4) * 8;
    unsigned short* oh = w2h + idx * 8;
    unsigned short* ol = w2l + idx * 8;
#pragma unroll
    for (int j = 0; j < 8; ++j) {
        splitw(src[(d0 + j) * 64 + o], &oh[j], &ol[j]);
    }
}

// ------------------------------------------------- [rows,64]@[64,64] GEMMs
// mode 0: xout = relu(xin@w + b), also write bf16 splits (lin0)
// mode 1: xout = relu(agg/max(cnt,1) + xin@w + b)          (NNConv root)
// mode 2: xout = xin@w (no bias, no relu)                  (Bn = x @ b2)
__global__ __launch_bounds__(256) void k_rowgemm(const float* __restrict__ xin,
                                                 const float* __restrict__ w,
                                                 const float* __restrict__ b,
                                                 const float* __restrict__ aggv,
                                                 const int* __restrict__ cntd,
                                                 float* __restrict__ xout,
                                                 unsigned short* __restrict__ xh,
                                                 unsigned short* __restrict__ xl,
                                                 int mode) {
    __shared__ float As[64][64];
    __shared__ float Ws[64][64];
    __shared__ float bs[64];
    int tid = threadIdx.x;
    int n0 = blockIdx.x * 64;
    for (int i = tid; i < 4096; i += 256) {
        As[i >> 6][i & 63] = xin[n0 * 64 + i];
        Ws[i >> 6][i & 63] = w[i];
    }
    if (tid < 64) bs[tid] = (mode == 2) ? 0.f : b[tid];
    __syncthreads();
    int o = tid & 63, rr = tid >> 6;
    float acc[16];
#pragma unroll
    for (int i = 0; i < 16; ++i) acc[i] = bs[o];
    for (int d = 0; d < 64; ++d) {
        float wv = Ws[d][o];
#pragma unroll
        for (int i = 0; i < 16; ++i) acc[i] += As[rr * 16 + i][d] * wv;
    }
    for (int i = 0; i < 16; ++i) {
        int n = n0 + rr * 16 + i;
        int idx = n * 64 + o;
        float v = acc[i];
        if (mode == 1) {
            float c = fmaxf((float)cntd[n], 1.f);
            v += aggv[idx] / c;
        }
        if (mode != 2) v = fmaxf(v, 0.f);
        xout[idx] = v;
        if (mode == 0) splitw(v, &xh[idx], &xl[idx]);
    }
}

// ------------------------------------------------- edge MLP h = relu(ea@w1+b1)
__global__ __launch_bounds__(256) void k_hgemm(const float* __restrict__ ea,
                                               const float* __restrict__ w1,
                                               const float* __restrict__ b1,
                                               float* __restrict__ h_all) {
    __shared__ float w1s[16][64];
    __shared__ float b1s[64];
    __shared__ float eas[64][16];
    int tid = threadIdx.x;
    int e0 = blockIdx.x * 64;
    for (int i = tid; i < 1024; i += 256) {
        w1s[i >> 6][i & 63] = w1[i];
        eas[i >> 4][i & 15] = ea[e0 * 16 + i];
    }
    if (tid < 64) b1s[tid] = b1[tid];
    __syncthreads();
    int o = tid & 63, r0 = (tid >> 6) * 16;
    for (int r = r0; r < r0 + 16; ++r) {
        float acc = b1s[o];
#pragma unroll
        for (int j = 0; j < 16; ++j) acc += eas[r][j] * w1s[j][o];
        h_all[(e0 + r) * 64 + o] = fmaxf(acc, 0.f);
    }
}

// ------------------------------------------------------------ fused NNConv
// phase 1 (per chunk c, wave w handles k = c*4+w): MFMA split-bf16
//   P[t][k_local][o] = sum_d x[n0+t][d] * w2[k][d*64+o]  (fp32 in LDS, dbuf)
// phase 2: per-edge msg accumulation in registers, atomic flush at end.
__global__ __launch_bounds__(256) void k_fused(
    const unsigned short* __restrict__ xh, const unsigned short* __restrict__ xl,
    const unsigned short* __restrict__ w2h, const unsigned short* __restrict__ w2l,
    const float* __restrict__ h_all, const float* __restrict__ bn_all,
    const int* __restrict__ soff, const int* __restrict__ ebs,
    const int* __restrict__ esrc, const int* __restrict__ edst,
    float* __restrict__ agg) {
    __shared__ __align__(16) float P[2][TNF][KC][64];   // 64 KB
    __shared__ int el_t[CAP];
    __shared__ int el_dst[CAP];
    __shared__ int el_e[CAP];

    const int tid = threadIdx.x;
    const int n0 = blockIdx.x * TNF;
    const int w = tid >> 6;       // wave 0..3
    const int lane = tid & 63;
    const int l15 = tid & 15;
    const int q = lane >> 4;      // quad within wave
    const int g = tid >> 4;       // 16-lane group 0..15

    // ---- edge meta staging
    const int e0 = soff[n0];
    const int cnt_full = soff[n0 + TNF] - e0;
    const int cnt = min(cnt_full, CAP);
    for (int i = tid; i < cnt; i += 256) {
        int e = ebs[e0 + i];
        el_t[i] = esrc[e] - n0;
        el_dst[i] = edst[e];
        el_e[i] = e;
    }

    // ---- A fragments in registers (whole block lifetime)
    s8v Ah[2][2], Al[2][2];   // [row-tile][k-step]
#pragma unroll
    for (int rt = 0; rt < 2; ++rt)
#pragma unroll
        for (int s = 0; s < 2; ++s) {
            int n = n0 + rt * 16 + l15;
            int d0 = s * 32 + q * 8;
            Ah[rt][s] = *(const s8v*)(xh + n * 64 + d0);
            Al[rt][s] = *(const s8v*)(xl + n * 64 + d0);
        }

    __syncthreads();

    // ---- register message accumulators (init = Bn[src])
    const int cpg = (cnt + 15) >> 4;
    const int ib = g * cpg;
    const int ie = min(ib + cpg, cnt);
    f4v m[MREG];
#pragma unroll
    for (int il = 0; il < MREG; ++il) {
        if (ib + il < ie)
            m[il] = *(const f4v*)(bn_all + (n0 + el_t[ib + il]) * 64 + l15 * 4);
    }

    for (int c = 0; c < NCH; ++c) {
        const int buf = c & 1;
        // ---- phase 1: MFMA into P[buf]
        {
            const int k = c * KC + w;
            f4v acc[4][2];
#pragma unroll
            for (int o16 = 0; o16 < 4; ++o16)
#pragma unroll
                for (int rt = 0; rt < 2; ++rt) acc[o16][rt] = (f4v)0.f;
#pragma unroll
            for (int s = 0; s < 2; ++s) {
#pragma unroll
                for (int o16 = 0; o16 < 4; ++o16) {
                    const int fo = (((k * 2 + s) * 4 + o16) * 64 + lane) * 8;
                    s8v Bh = *(const s8v*)(w2h + fo);
                    s8v Bl = *(const s8v*)(w2l + fo);
#pragma unroll
                    for (int rt = 0; rt < 2; ++rt) {
                        acc[o16][rt] = __builtin_amdgcn_mfma_f32_16x16x32_bf16(
                            Ah[rt][s], Bh, acc[o16][rt], 0, 0, 0);
                        acc[o16][rt] = __builtin_amdgcn_mfma_f32_16x16x32_bf16(
                            Ah[rt][s], Bl, acc[o16][rt], 0, 0, 0);
                        acc[o16][rt] = __builtin_amdgcn_mfma_f32_16x16x32_bf16(
                            Al[rt][s], Bh, acc[o16][rt], 0, 0, 0);
                    }
                }
            }
#pragma unroll
            for (int o16 = 0; o16 < 4; ++o16)
#pragma unroll
                for (int rt = 0; rt < 2; ++rt)
#pragma unroll
                    for (int r = 0; r < 4; ++r)
                        P[buf][rt * 16 + q * 4 + r][w][o16 * 16 + l15] = acc[o16][rt][r];
        }
        __syncthreads();
        // ---- phase 2: accumulate msg for this chunk from P[buf]
        {
            int tprev = -1;
            f4v p0 = (f4v)0.f, p1 = (f4v)0.f, p2 = (f4v)0.f, p3 = (f4v)0.f;
#pragma unroll
            for (int il = 0; il < MREG; ++il) {
                int i = ib + il;
                if (i < ie) {
                    int t = el_t[i];
                    if (t != tprev) {
                        p0 = *(const f4v*)&P[buf][t][0][l15 * 4];
                        p1 = *(const f4v*)&P[buf][t][1][l15 * 4];
                        p2 = *(const f4v*)&P[buf][t][2][l15 * 4];
                        p3 = *(const f4v*)&P[buf][t][3][l15 * 4];
                        tprev = t;
                    }
                    f4v hv = *(const f4v*)(h_all + el_e[i] * 64 + c * KC);
                    m[il] += p0 * hv[0] + p1 * hv[1] + p2 * hv[2] + p3 * hv[3];
                }
            }
            // rare overflow path (cnt_full > CAP): immediate atomics per chunk
            for (int i = CAP + g; i < cnt_full; i += 16) {
                int e = ebs[e0 + i];
                int t = esrc[e] - n0;
                int dn = edst[e];
                f4v q0 = *(const f4v*)&P[buf][t][0][l15 * 4];
                f4v q1 = *(const f4v*)&P[buf][t][1][l15 * 4];
                f4v q2 = *(const f4v*)&P[buf][t][2][l15 * 4];
                f4v q3 = *(const f4v*)&P[buf][t][3][l15 * 4];
                f4v hv = *(const f4v*)(h_all + e * 64 + c * KC);
                f4v part = q0 * hv[0] + q1 * hv[1] + q2 * hv[2] + q3 * hv[3];
                if (c == 0) part += *(const f4v*)(bn_all + (n0 + t) * 64 + l15 * 4);
                float* ap = agg + dn * 64 + l15 * 4;
                atomicAdd(ap + 0, part[0]);
                atomicAdd(ap + 1, part[1]);
                atomicAdd(ap + 2, part[2]);
                atomicAdd(ap + 3, part[3]);
            }
        }
        // no second barrier needed: next phase-1 writes P[buf^1]; all waves'
        // phase-2 reads of P[buf^1] (chunk c-1) completed before this chunk's
        // barrier.
    }

    // ---- flush register messages
#pragma unroll
    for (int il = 0; il < MREG; ++il) {
        int i = ib + il;
        if (i < ie) {
            float* ap = agg + el_dst[i] * 64 + l15 * 4;
            atomicAdd(ap + 0, m[il][0]);
            atomicAdd(ap + 1, m[il][1]);
            atomicAdd(ap + 2, m[il][2]);
            atomicAdd(ap + 3, m[il][3]);
        }
    }
}

// ---------------------------------------------------- GraphNorm (fused) + split
__global__ __launch_bounds__(256) void k_gn(const float* __restrict__ xc,
                                            float* __restrict__ x,
                                            const float* __restrict__ gnsc,
                                            const float* __restrict__ gw,
                                            const float* __restrict__ gb,
                                            unsigned short* __restrict__ xh,
                                            unsigned short* __restrict__ xl) {
    int g = blockIdx.x, tid = threadIdx.x;
    int c = tid & 63, rr = tid >> 6;
    __shared__ float S[4][64], S2[4][64], mv[64], rs[64];
    float s = 0.f, s2 = 0.f;
    for (int r = rr; r < 128; r += 4) {
        float v = xc[(g * 128 + r) * 64 + c];
        s += v; s2 += v * v;
    }
    S[rr][c] = s; S2[rr][c] = s2;
    __syncthreads();
    if (tid < 64) {
        float sum = S[0][tid] + S[1][tid] + S[2][tid] + S[3][tid];
        float sum2 = S2[0][tid] + S2[1][tid] + S2[2][tid] + S2[3][tid];
        float m = sum * (1.f / 128.f);
        float ex2 = sum2 * (1.f / 128.f);
        float sc = gnsc[tid];
        float var = ex2 - (2.f * sc - sc * sc) * m * m;
        mv[tid] = m;
        rs[tid] = rsqrtf(var + 1e-5f);
    }
    __syncthreads();
    float sc = gnsc[c], wv = gw[c], bv = gb[c], m = mv[c], rv = rs[c];
    for (int r = rr; r < 128; r += 4) {
        int idx = (g * 128 + r) * 64 + c;
        float xn = wv * (xc[idx] - sc * m) * rv + bv + x[idx];
        x[idx] = xn;
        splitw(xn, &xh[idx], &xl[idx]);
    }
}

// ------------------------------------- Set2Set (3 steps) + head, one kernel
__global__ __launch_bounds__(256) void k_s2s(const float* __restrict__ x,
                                             const float* __restrict__ wih,
                                             const float* __restrict__ whh,
                                             const float* __restrict__ bih,
                                             const float* __restrict__ bhh,
                                             const float* __restrict__ hw1,
                                             const float* __restrict__ hb1,
                                             const float* __restrict__ hw2,
                                             const float* __restrict__ hb2,
                                             float* __restrict__ out) {
    int g = blockIdx.x, tid = threadIdx.x;
    __shared__ float xg[128][64];      // 32 KB graph tile
    __shared__ float qs[128];
    __shared__ float hhS[64], ccS[64];
    __shared__ float gl[256];
    __shared__ float ev[128];
    __shared__ float S[4][64];
    __shared__ float red[2];
    for (int i = tid; i < 8192; i += 256)
        xg[i >> 6][i & 63] = x[(g * 128 + (i >> 6)) * 64 + (i & 63)];
    if (tid < 128) qs[tid] = 0.f;
    if (tid < 64) { hhS[tid] = 0.f; ccS[tid] = 0.f; }
    __syncthreads();

    for (int step = 0; step < 3; ++step) {
        // LSTM gates
        float acc = bih[tid] + bhh[tid];
        const float* wr = wih + tid * 128;
        for (int i = 0; i < 128; ++i) acc += qs[i] * wr[i];
        const float* w2r = whh + tid * 64;
        for (int i = 0; i < 64; ++i) acc += hhS[i] * w2r[i];
        gl[tid] = acc;
        __syncthreads();
        if (tid < 64) {
            float ig = 1.f / (1.f + expf(-gl[tid]));
            float fg = 1.f / (1.f + expf(-gl[64 + tid]));
            float gg = tanhf(gl[128 + tid]);
            float og = 1.f / (1.f + expf(-gl[192 + tid]));
            float cnew = fg * ccS[tid] + ig * gg;
            ccS[tid] = cnew;
            hhS[tid] = og * tanhf(cnew);
        }
        __syncthreads();
        // attention scores
        if (tid < 128) {
            float s = 0.f;
            for (int c = 0; c < 64; ++c) s += xg[tid][c] * hhS[c];
            ev[tid] = s;
        }
        __syncthreads();
        if (tid < 64) {
            float mx = fmaxf(ev[tid], ev[tid + 64]);
            for (int off = 32; off > 0; off >>= 1) mx = fmaxf(mx, __shfl_down(mx, off));
            if (tid == 0) red[0] = mx;
        }
        __syncthreads();
        float emax = red[0];
        if (tid < 128) ev[tid] = expf(ev[tid] - emax);
        __syncthreads();
        if (tid < 64) {
            float sm = ev[tid] + ev[tid + 64];
            for (int off = 32; off > 0; off >>= 1) sm += __shfl_down(sm, off);
            if (tid == 0) red[1] = sm;
        }
        __syncthreads();
        float denom = red[1];
        int c = tid & 63, rr = tid >> 6;
        float p = 0.f;
        for (int n = rr; n < 128; n += 4) p += ev[n] * xg[n][c];
        S[rr][c] = p;
        __syncthreads();
        if (tid < 64) {
            float r = (S[0][tid] + S[1][tid] + S[2][tid] + S[3][tid]) / denom;
            qs[tid] = hhS[tid];
            qs[64 + tid] = r;
        }
        __syncthreads();
    }

    // head
    if (tid < 64) {
        float acc = hb1[tid];
        for (int i = 0; i < 128; ++i) acc += qs[i] * hw1[i * 64 + tid];
        acc = fmaxf(acc, 0.f);
        float v = acc * hw2[tid];
        for (int off = 32; off > 0; off >>= 1) v += __shfl_down(v, off);
        if (tid == 0) out[g] = v + hb2[0];
    }
}

// -------------------------------------------------------------------- launch
extern "C" void kernel_launch(void* const* d_in, const int* in_sizes, int n_in,
                              void* d_out, int out_size, void* d_ws, size_t ws_size,
                              hipStream_t stream) {
    (void)in_sizes; (void)n_in; (void)out_size; (void)ws_size;
    const float* x_in  = (const float*)d_in[0];
    const int*   eidx  = (const int*)d_in[1];
    const float* eattr = (const float*)d_in[2];
    const float* lin0w = (const float*)d_in[4];
    const float* lin0b = (const float*)d_in[5];
    const float* mw1   = (const float*)d_in[6];
    const float* mb1   = (const float*)d_in[7];
    const float* mw2   = (const float*)d_in[8];
    const float* mb2   = (const float*)d_in[9];
    const float* rootw = (const float*)d_in[10];
    const float* convb = (const float*)d_in[11];
    const float* gnw   = (const float*)d_in[12];
    const float* gnb   = (const float*)d_in[13];
    const float* gnsc  = (const float*)d_in[14];
    const float* wih   = (const float*)d_in[15];
    const float* whh   = (const float*)d_in[16];
    const float* bih   = (const float*)d_in[17];
    const float* bhh   = (const float*)d_in[18];
    const float* hw1   = (const float*)d_in[19];
    const float* hb1   = (const float*)d_in[20];
    const float* hw2   = (const float*)d_in[21];
    const float* hb2   = (const float*)d_in[22];
    float* out = (float*)d_out;

    const int* esrc = eidx;
    const int* edst = eidx + N_EDGES;

    float* xb     = (float*)d_ws;                  // 1 M floats
    float* xcb    = xb + 1048576;                  // 1 M (aliases agg)
    float* agg    = xcb;                           // alias: safe (elementwise)
    float* bn_all = xcb + 1048576;                 // 1 M
    float* h_all  = bn_all + 1048576;              // 4 M
    unsigned short* xh  = (unsigned short*)(h_all + 4194304);  // 1 M us
    unsigned short* xl  = xh + 1048576;
    unsigned short* w2h = xl + 1048576;            // 786432 us
    unsigned short* w2l = w2h + 786432;
    int* deg    = (int*)(w2l + 786432);
    int* soff   = deg + N_NODES;
    int* cursor = soff + (N_NODES + 1);
    int* cntd   = cursor + N_NODES;
    int* ebs    = cntd + N_NODES;

    hipMemsetAsync(deg, 0, sizeof(int) * (4 * N_NODES + 1), stream);

    k_w2prep<<<384, 256, 0, stream>>>(mw2, w2h, w2l);
    k_hist<<<N_EDGES / 256, 256, 0, stream>>>(esrc, edst, deg, cntd);
    k_scan<<<1, 256, 0, stream>>>(deg, soff, cursor);
    k_fill<<<N_EDGES / 256, 256, 0, stream>>>(esrc, cursor, ebs);

    k_rowgemm<<<N_NODES / 64, 256, 0, stream>>>(x_in, lin0w, lin0b, nullptr, nullptr,
                                                xb, xh, xl, 0);

    for (int l = 0; l < 3; ++l) {
        k_hgemm<<<N_EDGES / 64, 256, 0, stream>>>(eattr, mw1 + l * 1024, mb1 + l * 64,
                                                  h_all);
        k_rowgemm<<<N_NODES / 64, 256, 0, stream>>>(xb, mb2 + l * 4096, nullptr, nullptr,
                                                    nullptr, bn_all, nullptr, nullptr, 2);
        hipMemsetAsync(agg, 0, sizeof(float) * N_NODES * 64, stream);
        k_fused<<<N_NODES / TNF, 256, 0, stream>>>(
            xh, xl, w2h + l * 262144, w2l + l * 262144,
            h_all, bn_all, soff, ebs, esrc, edst, agg);
        k_rowgemm<<<N_NODES / 64, 256, 0, stream>>>(xb, rootw + l * 4096, convb + l * 64,
                                                    agg, cntd, xcb, nullptr, nullptr, 1);
        k_gn<<<N_GRAPH, 256, 0, stream>>>(xcb, xb, gnsc + l * 64, gnw + l * 64,
                                          gnb + l * 64, xh, xl);
    }

    k_s2s<<<N_GRAPH, 256, 0, stream>>>(xb, wih, whh, bih, bhh,
                                       hw1, hb1, hw2, hb2, out);
}